// Round 18
// baseline (120.307 us; speedup 1.0000x reference)
//
#include <hip/hip_runtime.h>
#include <math.h>

#define B_ 8
#define T_ 4096
#define D_ 192
#define E_ 6
#define H_ 768            // 4*D
#define NTOK (B_*T_)      // 32768
#define NT 3              // expert types
#define TPB 64            // tokens per GEMM block-group
#define NJT 48            // rw1 column-tiles
#define NPK 49            // packed tiles (48 rw1 + 1 nw1)
#define NKS 6             // K steps of 32 (K=192)
#define NS  4             // j-splits per token group
#define PP2 128           // tokens per router_post block
#define NPB (NTOK/PP2)    // 256 post blocks

// ws float-offset layout
#define WS_TPART 0        // 3*768 (rb1 folded in)
#define WS_W2M   2304     // 768
#define WS_TEMP  3072
#define WS_RB2M  3073
#define WS_BP    4096                   // 49 tiles * 6144 ushorts = 150528 floats
#define WS_LOGP  (4096 + 150528)        // 4 splits * 32768*3 f32 (plain stores)
#define WS_NSC   (WS_LOGP + NS*98304)   // 32768*6 f32 noise scale
#define WS_ENTP  (WS_NSC + 196608)      // 256 f32 per-block entropy partials
#define WS_LOADP (WS_ENTP + 256)        // 256*6 f32 per-block load partials

typedef float  f32x4  __attribute__((ext_vector_type(4)));
typedef short  bf16x8 __attribute__((ext_vector_type(8)));

__device__ __forceinline__ ushort bf16rn(float f) {   // round-to-nearest-even bf16
    unsigned u = __float_as_uint(f);
    return (ushort)((u + 0x7FFFu + ((u >> 16) & 1u)) >> 16);
}

// async global->LDS, 16B per lane (dest = wave-uniform base + lane*16)
__device__ __forceinline__ void gll16(const void* g, void* lds) {
    __builtin_amdgcn_global_load_lds(
        (const __attribute__((address_space(1))) unsigned*)g,
        (__attribute__((address_space(3))) unsigned*)lds, 16, 0, 0);
}

// Fast erf (Abramowitz-Stegun 7.1.26): |err| <= 1.5e-7 (validated R4-R17).
__device__ __forceinline__ float gelu_f(float v) {
    float x  = v * 0.70710678118654752440f;
    float ax = fabsf(x);
    float t  = __builtin_amdgcn_rcpf(fmaf(0.3275911f, ax, 1.0f));
    float y  = t * fmaf(t, fmaf(t, fmaf(t, fmaf(t, 1.061405429f, -1.453152027f),
                                         1.421413741f), -0.284496736f), 0.254829592f);
    float em = __expf(-ax * ax);
    float er = fmaf(-y, em, 1.0f);
    er = copysignf(er, x);
    return 0.5f * v * (1.0f + er);
}
__device__ __forceinline__ float softplus_f(float x) {
    return fmaxf(x, 0.0f) + log1pf(expf(-fabsf(x)));
}

// prep (59 blocks): [0,49) B-pack 2-split (tile 48 = padded nw1); [49,58)
// tpart (unroll 8); 58 w2m+scalars. No LOGP zeroing needed (plain stores).
__global__ __launch_bounds__(256) void prep_kernel(
    const float* __restrict__ type_emb,    // (3, 384)
    const float* __restrict__ rw1,         // (576, 768)
    const float* __restrict__ rb1,         // (768)
    const float* __restrict__ rw2,         // (768, 6)
    const float* __restrict__ rb2,         // (6)
    const float* __restrict__ temperature, // (1)
    const float* __restrict__ nw1,         // (192, 12)
    float* __restrict__ wsF)
{
    int blk = blockIdx.x, tid = threadIdx.x;
    if (blk < NPK) {
        int nt = blk;
        ushort* Bp = (ushort*)(wsF + WS_BP);
        int col = tid & 15;                         // coalesced reads: 16 cols/row
        for (int kr = tid >> 4; kr < D_; kr += 16) {
            float a;
            if (nt < NJT) a = rw1[(size_t)kr * H_ + nt * 16 + col];
            else          a = (col < 12) ? nw1[kr * 12 + col] : 0.0f;
            ushort s1 = bf16rn(a);  float f1 = __uint_as_float((unsigned)s1 << 16);
            float r1 = a - f1;
            ushort s2 = bf16rn(r1);
            // b = b1 + b2 (2-split; residual ~2^-19 rel -> logit err ~5e-8)
            // B-frag layout: lane l holds B[k= ks*32+(l>>4)*8+i][col= l&15]
            int ks = kr >> 5, kg = (kr >> 3) & 3, i = kr & 7;
            int l  = (kg << 4) | col;
            size_t base = (size_t)nt * 6144 + (size_t)((ks * 2) * 64 + l) * 8 + i;
            Bp[base]       = s1;                    // spl 0
            Bp[base + 512] = s2;                    // spl 1 (+64 lanes*8)
        }
    } else if (blk < NPK + 9) {
        int o = (blk - NPK) * 256 + tid;            // 0..2303
        int c = o / H_, j = o % H_;
        float s = rb1[j];
        const float* te = type_emb + c * (2 * D_);
        #pragma unroll 8
        for (int k = 0; k < 2 * D_; ++k)
            s = fmaf(te[k], rw1[(size_t)(D_ + k) * H_ + j], s);
        wsF[WS_TPART + o] = s;
    } else {
        for (int j = tid; j < H_; j += 256) {
            float s = 0.f;
            #pragma unroll
            for (int e = 0; e < E_; ++e) s += rw2[(size_t)j * E_ + e];
            wsF[WS_W2M + j] = s * (1.0f / 6.0f);
        }
        if (tid == 0) {
            float decay = (float)pow(0.95, (double)(T_ / 100));   // 0.95^40
            float tv = temperature[0] * decay;
            wsF[WS_TEMP] = fminf(fmaxf(tv, 0.05f), 3.0f);
            float rs = 0.f;
            #pragma unroll
            for (int e = 0; e < E_; ++e) rs += rb2[e];
            wsF[WS_RB2M] = rs * (1.0f / 6.0f);
        }
    }
}

// R18 GEMM: 4-way j-split (grid 2048; group (4m..4m+3) = same 64 tokens,
// splits of the 49 tiles: s0={0..11,48}, s1..s3 = 12 each). Partial logits
// go to LOGP[split][token][c] via PLAIN STORES — each slot written by exactly
// one block: no atomics, no zeroing, deterministic (R17's 2-adder atomicAdd
// RMW traffic removed; post sums the 4 partials in fixed order). 2x block
// supply of R17 (8/CU issued, 5 resident by 28KB LDS) -> higher VALU overlap.
__global__ __launch_bounds__(256, 3) void router_mfma(
    const float* __restrict__ x,            // (32768, 192)
    const float* __restrict__ nb1,          // (12)
    const float* __restrict__ nw2,          // (12, 6)
    const float* __restrict__ nb2,          // (6)
    float* __restrict__ wsF)
{
    __shared__ float4 Bst[2][768];      // 24 KB double-buffered B tile
    __shared__ float h1L[TPB][12];      // 3 KB (split-0 only)
    __shared__ float nw2L[72];
    __shared__ float nb1L[12];
    __shared__ float nb2L[E_];

    int tid = threadIdx.x;
    int wave = tid >> 6, lane = tid & 63;
    int groupid = blockIdx.x >> 2;
    int split   = blockIdx.x & 3;
    int tok0    = groupid * TPB;
    int jc = lane & 15;

    if (tid < 72) nw2L[tid] = nw2[tid];
    if (tid < 12) nb1L[tid] = nb1[tid];
    if (tid < E_) nb2L[tid] = nb2[tid];

    // ---- A fragments: lane holds token row tok0+wave*16+jc, k=ks*32+(lane>>4)*8+i.
    // 3-way bf16 split of x (validated R8+); 72 VGPR, loop-invariant.
    int tok = tok0 + (wave << 4) + jc;
    int kg  = (lane >> 4) << 3;
    bf16x8 a1[NKS], a2[NKS], a3[NKS];
    #pragma unroll
    for (int ks = 0; ks < NKS; ++ks) {
        const float* xp = x + (size_t)tok * D_ + ks * 32 + kg;
        float4 v0 = *(const float4*)xp;
        float4 v1 = *(const float4*)(xp + 4);
        float f[8] = {v0.x, v0.y, v0.z, v0.w, v1.x, v1.y, v1.z, v1.w};
        #pragma unroll
        for (int i = 0; i < 8; ++i) {
            float a = f[i];
            ushort s1 = bf16rn(a);  float f1 = __uint_as_float((unsigned)s1 << 16);
            float r1 = a - f1;
            ushort s2 = bf16rn(r1); float f2 = __uint_as_float((unsigned)s2 << 16);
            float r2 = r1 - f2;
            a1[ks][i] = (short)s1; a2[ks][i] = (short)s2; a3[ks][i] = (short)bf16rn(r2);
        }
    }

    float la0[4] = {0,0,0,0}, la1[4] = {0,0,0,0}, la2[4] = {0,0,0,0};
    const ushort* Bp = (const ushort*)(wsF + WS_BP);

    // tile lists: split 0 -> {0..11, 48} (13), split s>0 -> {12s..12s+11} (12)
    int NGh = (split == 0) ? 13 : 12;
    int rot = (blockIdx.x >> 3) % NGh;   // decorrelate co-XCD blocks (R6 lesson)

#define TILE_ID(L) ((split == 0) ? (((L) < 12) ? (L) : NJT) : (split * 12 + (L)))
#define STAGE(ntv, bufv) { \
    const float4* sp_ = (const float4*)(Bp + (size_t)(ntv) * 6144); \
    float4* dp_ = &Bst[bufv][0]; \
    gll16(sp_ + tid, dp_ + tid); \
    gll16(sp_ + tid + 256, dp_ + tid + 256); \
    gll16(sp_ + tid + 512, dp_ + tid + 512); }

    STAGE(TILE_ID(rot), 0);
    __syncthreads();

    for (int it = 0; it < NGh; ++it) {
        int l0 = rot + it; if (l0 >= NGh) l0 -= NGh;
        int nt = TILE_ID(l0);
        if (it + 1 < NGh) {
            int l1 = rot + it + 1; if (l1 >= NGh) l1 -= NGh;
            STAGE(TILE_ID(l1), (it + 1) & 1);
        }

        const bf16x8* bp = (const bf16x8*)&Bst[it & 1][0];
        f32x4 c0 = {0,0,0,0}, c1 = {0,0,0,0}, c2 = {0,0,0,0},
              c3 = {0,0,0,0}, c4 = {0,0,0,0};
        #pragma unroll
        for (int ks = 0; ks < NKS; ++ks) {
            bf16x8 b1 = bp[(ks * 2 + 0) * 64 + lane];
            bf16x8 b2 = bp[(ks * 2 + 1) * 64 + lane];
            // 5 products, independent accumulators (R13 lesson)
            c0 = __builtin_amdgcn_mfma_f32_16x16x32_bf16(a1[ks], b1, c0, 0, 0, 0);
            c1 = __builtin_amdgcn_mfma_f32_16x16x32_bf16(a1[ks], b2, c1, 0, 0, 0);
            c2 = __builtin_amdgcn_mfma_f32_16x16x32_bf16(a2[ks], b1, c2, 0, 0, 0);
            c3 = __builtin_amdgcn_mfma_f32_16x16x32_bf16(a2[ks], b2, c3, 0, 0, 0);
            c4 = __builtin_amdgcn_mfma_f32_16x16x32_bf16(a3[ks], b1, c4, 0, 0, 0);
        }
        // D layout: row=(lane>>4)*4+r (token-local), col=lane&15
        if (nt < NJT) {
            int j = nt * 16 + jc;
            float w2v = wsF[WS_W2M + j];          // global, L2 (decorrelated)
            float t0  = wsF[WS_TPART + j];
            float t1  = wsF[WS_TPART + H_ + j];
            float t2  = wsF[WS_TPART + 2 * H_ + j];
            #pragma unroll
            for (int r = 0; r < 4; ++r) {
                float xv = ((c0[r] + c1[r]) + (c2[r] + c3[r])) + c4[r];
                la0[r] += gelu_f(xv + t0) * w2v;
                la1[r] += gelu_f(xv + t1) * w2v;
                la2[r] += gelu_f(xv + t2) * w2v;
            }
        } else if (jc < 12) {                     // nw1 tile (split 0 only)
            float bb = nb1L[jc];
            #pragma unroll
            for (int r = 0; r < 4; ++r) {
                float xv = ((c0[r] + c1[r]) + (c2[r] + c3[r])) + c4[r];
                int tl = (wave << 4) + ((lane >> 4) << 2) + r;
                h1L[tl][jc] = gelu_f(xv + bb);
            }
        }
        __syncthreads();            // single barrier per tile (R10-verified)
    }

    // ---- partial logits: 16-lane butterfly, plain store to this split's slot
    #pragma unroll
    for (int r = 0; r < 4; ++r) {
        float v0 = la0[r], v1 = la1[r], v2 = la2[r];
        #pragma unroll
        for (int off = 1; off < 16; off <<= 1) {
            v0 += __shfl_xor(v0, off, 64);
            v1 += __shfl_xor(v1, off, 64);
            v2 += __shfl_xor(v2, off, 64);
        }
        if (jc == 0) {
            int t = tok0 + (wave << 4) + ((lane >> 4) << 2) + r;
            size_t o = (size_t)(split * NTOK + t) * NT;
            wsF[WS_LOGP + o + 0] = v0;
            wsF[WS_LOGP + o + 1] = v1;
            wsF[WS_LOGP + o + 2] = v2;
        }
    }

    // ---- split 0: noise-MLP layer 2 -> nscale to ws (distinct addresses)
    if (split == 0) {
        for (int idx = tid; idx < TPB * E_; idx += 256) {
            int t = idx / E_, e = idx - t * E_;
            float s = nb2L[e];
            #pragma unroll
            for (int i2 = 0; i2 < 12; ++i2) s = fmaf(h1L[t][i2], nw2L[i2 * E_ + e], s);
            wsF[WS_NSC + (size_t)(tok0 + t) * E_ + e] = softplus_f(softplus_f(s));
        }
    }
}

// R18 post: thin (R17-proven: 155us -> ~6us once x-reads and same-address
// atomics were removed). Logits = fixed-order sum of the 4 split partials.
__global__ __launch_bounds__(128) void router_post(
    const float* __restrict__ noise,        // (32768, 6)
    const int*   __restrict__ expert_types, // (6)
    float* __restrict__ wsF,
    float* __restrict__ out)
{
    __shared__ unsigned loadL[E_];
    __shared__ float entW[2];

    int tid = threadIdx.x;                  // 128 threads = 128 tokens
    int tok = blockIdx.x * PP2 + tid;
    if (tid < E_) loadL[tid] = 0u;
    __syncthreads();

    float temp = wsF[WS_TEMP];
    float rb2m = wsF[WS_RB2M];
    float lg[NT];
    #pragma unroll
    for (int c = 0; c < NT; ++c) {
        float s0 = wsF[WS_LOGP + (size_t)(0 * NTOK + tok) * NT + c];
        float s1 = wsF[WS_LOGP + (size_t)(1 * NTOK + tok) * NT + c];
        float s2 = wsF[WS_LOGP + (size_t)(2 * NTOK + tok) * NT + c];
        float s3 = wsF[WS_LOGP + (size_t)(3 * NTOK + tok) * NT + c];
        lg[c] = ((s0 + s1) + (s2 + s3)) + rb2m;   // fixed order: deterministic
    }

    float nv[E_];
    #pragma unroll
    for (int e = 0; e < E_; ++e) {
        int ety = expert_types[e];
        float nsc = wsF[WS_NSC + (size_t)tok * E_ + e];
        nv[e] = lg[ety] + ((ety == 1) ? 0.3f : 0.0f)
              + temp * (noise[(size_t)tok * E_ + e] * nsc);
    }
    // top-2, ties -> lower index first (strict > keeps earliest)
    float v1 = -1e30f; int i1 = 0;
    #pragma unroll
    for (int e = 0; e < E_; ++e) if (nv[e] > v1) { v1 = nv[e]; i1 = e; }
    float v2 = -1e30f; int i2 = 0;
    #pragma unroll
    for (int e = 0; e < E_; ++e) {
        if (e == i1) continue;
        if (nv[e] > v2) { v2 = nv[e]; i2 = e; }
    }
    float e2 = expf(v2 - v1);
    float den = 1.0f + e2;
    float p1 = 1.0f / den, p2 = e2 / den;
    float ent = -(p1 * logf(p1 + 1e-8f) + p2 * logf(p2 + 1e-8f));

    #pragma unroll
    for (int e = 0; e < E_; ++e) {
        float v = 0.f;
        if (e == i1) v = p1; else if (e == i2) v = p2;
        out[(size_t)tok * E_ + e] = v;
    }
    out[(size_t)NTOK * E_ + (size_t)tok * 2]     = (float)i1;
    out[(size_t)NTOK * E_ + (size_t)tok * 2 + 1] = (float)i2;

    atomicAdd(&loadL[i1], 1u);              // LDS atomics: cheap, deterministic
    atomicAdd(&loadL[i2], 1u);
    // entropy: fixed-order butterfly within each wave, then wave partials
    #pragma unroll
    for (int off = 32; off; off >>= 1) ent += __shfl_xor(ent, off, 64);
    if ((tid & 63) == 0) entW[tid >> 6] = ent;
    __syncthreads();
    if (tid == 0) wsF[WS_ENTP + blockIdx.x] = entW[0] + entW[1];
    if (tid < E_) wsF[WS_LOADP + (size_t)blockIdx.x * E_ + tid] = (float)loadL[tid];
}

// finalize: one wave reduces 256 per-block partials (fixed order, determ.)
__global__ __launch_bounds__(64) void finalize_kernel(
    const float* __restrict__ wsF, float* __restrict__ out)
{
    int lane = threadIdx.x;                 // 64
    float ent = 0.f, ld[E_] = {0,0,0,0,0,0};
    #pragma unroll
    for (int q = 0; q < NPB / 64; ++q) {    // 4 blocks per lane
        int blk = lane * (NPB / 64) + q;
        ent += wsF[WS_ENTP + blk];
        #pragma unroll
        for (int e = 0; e < E_; ++e) ld[e] += wsF[WS_LOADP + (size_t)blk * E_ + e];
    }
    #pragma unroll
    for (int off = 32; off; off >>= 1) {
        ent += __shfl_xor(ent, off, 64);
        #pragma unroll
        for (int e = 0; e < E_; ++e) ld[e] += __shfl_xor(ld[e], off, 64);
    }
    if (lane == 0) {
        double m = 0.0;
        #pragma unroll
        for (int e = 0; e < E_; ++e) m += (double)ld[e];
        m /= (double)E_;
        double var = 0.0;
        #pragma unroll
        for (int e = 0; e < E_; ++e) { double d = (double)ld[e] - m; var += d * d; }
        var /= (double)(E_ - 1);
        // std(importance) == 0 exactly (top-2 always picks 2 of 6)
        double entm = (double)ent / (double)NTOK;
        out[(size_t)NTOK * E_ + (size_t)NTOK * 2] =
            (float)(0.1 * entm + 0.2 * sqrt(var));
    }
}

extern "C" void kernel_launch(void* const* d_in, const int* in_sizes, int n_in,
                              void* d_out, int out_size, void* d_ws, size_t ws_size,
                              hipStream_t stream)
{
    const float* x            = (const float*)d_in[0];
    const float* noise        = (const float*)d_in[1];
    const int*   expert_types = (const int*)  d_in[2];
    const float* type_emb     = (const float*)d_in[3];
    const float* nw1          = (const float*)d_in[4];
    const float* nb1          = (const float*)d_in[5];
    const float* nw2          = (const float*)d_in[6];
    const float* nb2          = (const float*)d_in[7];
    const float* rw1          = (const float*)d_in[8];
    const float* rb1          = (const float*)d_in[9];
    const float* rw2          = (const float*)d_in[10];
    const float* rb2          = (const float*)d_in[11];
    const float* temperature  = (const float*)d_in[12];
    float* out = (float*)d_out;
    float* wsF = (float*)d_ws;

    prep_kernel<<<NPK + 10, 256, 0, stream>>>(type_emb, rw1, rb1, rw2, rb2,
                                              temperature, nw1, wsF);
    router_mfma<<<(NTOK / TPB) * NS, 256, 0, stream>>>(x, nb1, nw2, nb2, wsF);
    router_post<<<NPB, 128, 0, stream>>>(noise, expert_types, wsF, out);
    finalize_kernel<<<1, 64, 0, stream>>>(wsF, out);
}

// Round 19
// 109.668 us; speedup vs baseline: 1.0970x; 1.0970x over previous
//
#include <hip/hip_runtime.h>
#include <math.h>

#define B_ 8
#define T_ 4096
#define D_ 192
#define E_ 6
#define H_ 768            // 4*D
#define NTOK (B_*T_)      // 32768
#define NT 3              // expert types
#define TPB 64            // tokens per GEMM block-pair
#define NJT 48            // rw1 column-tiles
#define NPK 49            // packed tiles (48 rw1 + 1 nw1)
#define NKS 6             // K steps of 32 (K=192)
#define NS  2             // j-splits per token group (R18's 4-way regressed: A-build duplication)
#define PP2 128           // tokens per router_post block
#define NPB (NTOK/PP2)    // 256 post blocks

// ws float-offset layout
#define WS_TPART 0        // 3*768 (rb1 folded in)
#define WS_W2M   2304     // 768
#define WS_TEMP  3072
#define WS_RB2M  3073
#define WS_BP    4096                   // 49 tiles * 6144 ushorts = 150528 floats
#define WS_LOGP  (4096 + 150528)        // 2 splits * 32768*3 f32 (plain stores)
#define WS_NSC   (WS_LOGP + NS*98304)   // 32768*6 f32 noise scale
#define WS_ENTP  (WS_NSC + 196608)      // 256 f32 per-block entropy partials
#define WS_LOADP (WS_ENTP + 256)        // 256*6 f32 per-block load partials

typedef float  f32x4  __attribute__((ext_vector_type(4)));
typedef short  bf16x8 __attribute__((ext_vector_type(8)));

__device__ __forceinline__ ushort bf16rn(float f) {   // round-to-nearest-even bf16
    unsigned u = __float_as_uint(f);
    return (ushort)((u + 0x7FFFu + ((u >> 16) & 1u)) >> 16);
}

// async global->LDS, 16B per lane (dest = wave-uniform base + lane*16)
__device__ __forceinline__ void gll16(const void* g, void* lds) {
    __builtin_amdgcn_global_load_lds(
        (const __attribute__((address_space(1))) unsigned*)g,
        (__attribute__((address_space(3))) unsigned*)lds, 16, 0, 0);
}

// Fast erf (Abramowitz-Stegun 7.1.26): |err| <= 1.5e-7 (validated R4-R18).
__device__ __forceinline__ float gelu_f(float v) {
    float x  = v * 0.70710678118654752440f;
    float ax = fabsf(x);
    float t  = __builtin_amdgcn_rcpf(fmaf(0.3275911f, ax, 1.0f));
    float y  = t * fmaf(t, fmaf(t, fmaf(t, fmaf(t, 1.061405429f, -1.453152027f),
                                         1.421413741f), -0.284496736f), 0.254829592f);
    float em = __expf(-ax * ax);
    float er = fmaf(-y, em, 1.0f);
    er = copysignf(er, x);
    return 0.5f * v * (1.0f + er);
}
__device__ __forceinline__ float softplus_f(float x) {
    return fmaxf(x, 0.0f) + log1pf(expf(-fabsf(x)));
}

// prep (59 blocks): [0,49) B-pack 2-split (tile 48 = padded nw1); [49,58)
// tpart (unroll 8); 58 w2m+scalars. No LOGP zeroing (plain stores).
__global__ __launch_bounds__(256) void prep_kernel(
    const float* __restrict__ type_emb,    // (3, 384)
    const float* __restrict__ rw1,         // (576, 768)
    const float* __restrict__ rb1,         // (768)
    const float* __restrict__ rw2,         // (768, 6)
    const float* __restrict__ rb2,         // (6)
    const float* __restrict__ temperature, // (1)
    const float* __restrict__ nw1,         // (192, 12)
    float* __restrict__ wsF)
{
    int blk = blockIdx.x, tid = threadIdx.x;
    if (blk < NPK) {
        int nt = blk;
        ushort* Bp = (ushort*)(wsF + WS_BP);
        int col = tid & 15;                         // coalesced reads: 16 cols/row
        for (int kr = tid >> 4; kr < D_; kr += 16) {
            float a;
            if (nt < NJT) a = rw1[(size_t)kr * H_ + nt * 16 + col];
            else          a = (col < 12) ? nw1[kr * 12 + col] : 0.0f;
            ushort s1 = bf16rn(a);  float f1 = __uint_as_float((unsigned)s1 << 16);
            float r1 = a - f1;
            ushort s2 = bf16rn(r1);
            // b = b1 + b2 (2-split; residual ~2^-19 rel -> logit err ~5e-8)
            // B-frag layout: lane l holds B[k= ks*32+(l>>4)*8+i][col= l&15]
            int ks = kr >> 5, kg = (kr >> 3) & 3, i = kr & 7;
            int l  = (kg << 4) | col;
            size_t base = (size_t)nt * 6144 + (size_t)((ks * 2) * 64 + l) * 8 + i;
            Bp[base]       = s1;                    // spl 0
            Bp[base + 512] = s2;                    // spl 1 (+64 lanes*8)
        }
    } else if (blk < NPK + 9) {
        int o = (blk - NPK) * 256 + tid;            // 0..2303
        int c = o / H_, j = o % H_;
        float s = rb1[j];
        const float* te = type_emb + c * (2 * D_);
        #pragma unroll 8
        for (int k = 0; k < 2 * D_; ++k)
            s = fmaf(te[k], rw1[(size_t)(D_ + k) * H_ + j], s);
        wsF[WS_TPART + o] = s;
    } else {
        for (int j = tid; j < H_; j += 256) {
            float s = 0.f;
            #pragma unroll
            for (int e = 0; e < E_; ++e) s += rw2[(size_t)j * E_ + e];
            wsF[WS_W2M + j] = s * (1.0f / 6.0f);
        }
        if (tid == 0) {
            float decay = (float)pow(0.95, (double)(T_ / 100));   // 0.95^40
            float tv = temperature[0] * decay;
            wsF[WS_TEMP] = fminf(fmaxf(tv, 0.05f), 3.0f);
            float rs = 0.f;
            #pragma unroll
            for (int e = 0; e < E_; ++e) rs += rb2[e];
            wsF[WS_RB2M] = rs * (1.0f / 6.0f);
        }
    }
}

// R19 GEMM: R17's proven 2-way j-split (router 95us — best measured; R18's
// 4-way regressed to 108 by duplicating A-build + x reads), with R18's one
// good piece kept: partial logits via PLAIN STORES to LOGP[half][tok][c]
// (each slot written by exactly one block: no atomic RMW round trips through
// the non-coherent L2s, no zeroing pass, deterministic fixed-order sum in
// post). R17's atomics cost ~17MB WRITE + ~13MB FETCH of RMW traffic.
__global__ __launch_bounds__(256, 3) void router_mfma(
    const float* __restrict__ x,            // (32768, 192)
    const float* __restrict__ nb1,          // (12)
    const float* __restrict__ nw2,          // (12, 6)
    const float* __restrict__ nb2,          // (6)
    float* __restrict__ wsF)
{
    __shared__ float4 Bst[2][768];      // 24 KB double-buffered B tile
    __shared__ float h1L[TPB][12];      // 3 KB (half-0 only)
    __shared__ float nw2L[72];
    __shared__ float nb1L[12];
    __shared__ float nb2L[E_];

    int tid = threadIdx.x;
    int wave = tid >> 6, lane = tid & 63;
    int pairid = blockIdx.x >> 1;
    int half   = blockIdx.x & 1;
    int tok0   = pairid * TPB;
    int jc = lane & 15;

    if (tid < 72) nw2L[tid] = nw2[tid];
    if (tid < 12) nb1L[tid] = nb1[tid];
    if (tid < E_) nb2L[tid] = nb2[tid];

    // ---- A fragments: lane holds token row tok0+wave*16+jc, k=ks*32+(lane>>4)*8+i.
    // 3-way bf16 split of x (validated R8+); 72 VGPR, loop-invariant.
    int tok = tok0 + (wave << 4) + jc;
    int kg  = (lane >> 4) << 3;
    bf16x8 a1[NKS], a2[NKS], a3[NKS];
    #pragma unroll
    for (int ks = 0; ks < NKS; ++ks) {
        const float* xp = x + (size_t)tok * D_ + ks * 32 + kg;
        float4 v0 = *(const float4*)xp;
        float4 v1 = *(const float4*)(xp + 4);
        float f[8] = {v0.x, v0.y, v0.z, v0.w, v1.x, v1.y, v1.z, v1.w};
        #pragma unroll
        for (int i = 0; i < 8; ++i) {
            float a = f[i];
            ushort s1 = bf16rn(a);  float f1 = __uint_as_float((unsigned)s1 << 16);
            float r1 = a - f1;
            ushort s2 = bf16rn(r1); float f2 = __uint_as_float((unsigned)s2 << 16);
            float r2 = r1 - f2;
            a1[ks][i] = (short)s1; a2[ks][i] = (short)s2; a3[ks][i] = (short)bf16rn(r2);
        }
    }

    float la0[4] = {0,0,0,0}, la1[4] = {0,0,0,0}, la2[4] = {0,0,0,0};
    const ushort* Bp = (const ushort*)(wsF + WS_BP);

    // tile lists: half 0 -> {0..23, 48} (25), half 1 -> {24..47} (24)
    int NGh = half ? 24 : 25;
    int rot = (blockIdx.x >> 3) % NGh;   // decorrelate co-XCD blocks (R6 lesson)

#define TILE_ID(L) (half ? (24 + (L)) : ((L) < 24 ? (L) : NJT))
#define STAGE(ntv, bufv) { \
    const float4* sp_ = (const float4*)(Bp + (size_t)(ntv) * 6144); \
    float4* dp_ = &Bst[bufv][0]; \
    gll16(sp_ + tid, dp_ + tid); \
    gll16(sp_ + tid + 256, dp_ + tid + 256); \
    gll16(sp_ + tid + 512, dp_ + tid + 512); }

    STAGE(TILE_ID(rot), 0);
    __syncthreads();

    for (int it = 0; it < NGh; ++it) {
        int l0 = rot + it; if (l0 >= NGh) l0 -= NGh;
        int nt = TILE_ID(l0);
        if (it + 1 < NGh) {
            int l1 = rot + it + 1; if (l1 >= NGh) l1 -= NGh;
            STAGE(TILE_ID(l1), (it + 1) & 1);
        }

        const bf16x8* bp = (const bf16x8*)&Bst[it & 1][0];
        f32x4 c0 = {0,0,0,0}, c1 = {0,0,0,0}, c2 = {0,0,0,0},
              c3 = {0,0,0,0}, c4 = {0,0,0,0};
        #pragma unroll
        for (int ks = 0; ks < NKS; ++ks) {
            bf16x8 b1 = bp[(ks * 2 + 0) * 64 + lane];
            bf16x8 b2 = bp[(ks * 2 + 1) * 64 + lane];
            // 5 products, independent accumulators (R13 lesson)
            c0 = __builtin_amdgcn_mfma_f32_16x16x32_bf16(a1[ks], b1, c0, 0, 0, 0);
            c1 = __builtin_amdgcn_mfma_f32_16x16x32_bf16(a1[ks], b2, c1, 0, 0, 0);
            c2 = __builtin_amdgcn_mfma_f32_16x16x32_bf16(a2[ks], b1, c2, 0, 0, 0);
            c3 = __builtin_amdgcn_mfma_f32_16x16x32_bf16(a2[ks], b2, c3, 0, 0, 0);
            c4 = __builtin_amdgcn_mfma_f32_16x16x32_bf16(a3[ks], b1, c4, 0, 0, 0);
        }
        // D layout: row=(lane>>4)*4+r (token-local), col=lane&15
        if (nt < NJT) {
            int j = nt * 16 + jc;
            float w2v = wsF[WS_W2M + j];          // global, L2 (decorrelated)
            float t0  = wsF[WS_TPART + j];
            float t1  = wsF[WS_TPART + H_ + j];
            float t2  = wsF[WS_TPART + 2 * H_ + j];
            #pragma unroll
            for (int r = 0; r < 4; ++r) {
                float xv = ((c0[r] + c1[r]) + (c2[r] + c3[r])) + c4[r];
                la0[r] += gelu_f(xv + t0) * w2v;
                la1[r] += gelu_f(xv + t1) * w2v;
                la2[r] += gelu_f(xv + t2) * w2v;
            }
        } else if (jc < 12) {                     // nw1 tile (half 0 only)
            float bb = nb1L[jc];
            #pragma unroll
            for (int r = 0; r < 4; ++r) {
                float xv = ((c0[r] + c1[r]) + (c2[r] + c3[r])) + c4[r];
                int tl = (wave << 4) + ((lane >> 4) << 2) + r;
                h1L[tl][jc] = gelu_f(xv + bb);
            }
        }
        __syncthreads();            // single barrier per tile (R10-verified)
    }

    // ---- partial logits: 16-lane butterfly, plain store to this half's slot
    #pragma unroll
    for (int r = 0; r < 4; ++r) {
        float v0 = la0[r], v1 = la1[r], v2 = la2[r];
        #pragma unroll
        for (int off = 1; off < 16; off <<= 1) {
            v0 += __shfl_xor(v0, off, 64);
            v1 += __shfl_xor(v1, off, 64);
            v2 += __shfl_xor(v2, off, 64);
        }
        if (jc == 0) {
            int t = tok0 + (wave << 4) + ((lane >> 4) << 2) + r;
            size_t o = (size_t)(half * NTOK + t) * NT;
            wsF[WS_LOGP + o + 0] = v0;
            wsF[WS_LOGP + o + 1] = v1;
            wsF[WS_LOGP + o + 2] = v2;
        }
    }

    // ---- half 0: noise-MLP layer 2 -> nscale to ws (distinct addresses)
    if (half == 0) {
        for (int idx = tid; idx < TPB * E_; idx += 256) {
            int t = idx / E_, e = idx - t * E_;
            float s = nb2L[e];
            #pragma unroll
            for (int i2 = 0; i2 < 12; ++i2) s = fmaf(h1L[t][i2], nw2L[i2 * E_ + e], s);
            wsF[WS_NSC + (size_t)(tok0 + t) * E_ + e] = softplus_f(softplus_f(s));
        }
    }
}

// R19 post: thin (R17-proven). Logits = fixed-order sum of the 2 half partials.
__global__ __launch_bounds__(128) void router_post(
    const float* __restrict__ noise,        // (32768, 6)
    const int*   __restrict__ expert_types, // (6)
    float* __restrict__ wsF,
    float* __restrict__ out)
{
    __shared__ unsigned loadL[E_];
    __shared__ float entW[2];

    int tid = threadIdx.x;                  // 128 threads = 128 tokens
    int tok = blockIdx.x * PP2 + tid;
    if (tid < E_) loadL[tid] = 0u;
    __syncthreads();

    float temp = wsF[WS_TEMP];
    float rb2m = wsF[WS_RB2M];
    float lg[NT];
    #pragma unroll
    for (int c = 0; c < NT; ++c) {
        float s0 = wsF[WS_LOGP + (size_t)tok * NT + c];
        float s1 = wsF[WS_LOGP + (size_t)(NTOK + tok) * NT + c];
        lg[c] = (s0 + s1) + rb2m;           // fixed order: deterministic
    }

    float nv[E_];
    #pragma unroll
    for (int e = 0; e < E_; ++e) {
        int ety = expert_types[e];
        float nsc = wsF[WS_NSC + (size_t)tok * E_ + e];
        nv[e] = lg[ety] + ((ety == 1) ? 0.3f : 0.0f)
              + temp * (noise[(size_t)tok * E_ + e] * nsc);
    }
    // top-2, ties -> lower index first (strict > keeps earliest)
    float v1 = -1e30f; int i1 = 0;
    #pragma unroll
    for (int e = 0; e < E_; ++e) if (nv[e] > v1) { v1 = nv[e]; i1 = e; }
    float v2 = -1e30f; int i2 = 0;
    #pragma unroll
    for (int e = 0; e < E_; ++e) {
        if (e == i1) continue;
        if (nv[e] > v2) { v2 = nv[e]; i2 = e; }
    }
    float e2 = expf(v2 - v1);
    float den = 1.0f + e2;
    float p1 = 1.0f / den, p2 = e2 / den;
    float ent = -(p1 * logf(p1 + 1e-8f) + p2 * logf(p2 + 1e-8f));

    #pragma unroll
    for (int e = 0; e < E_; ++e) {
        float v = 0.f;
        if (e == i1) v = p1; else if (e == i2) v = p2;
        out[(size_t)tok * E_ + e] = v;
    }
    out[(size_t)NTOK * E_ + (size_t)tok * 2]     = (float)i1;
    out[(size_t)NTOK * E_ + (size_t)tok * 2 + 1] = (float)i2;

    atomicAdd(&loadL[i1], 1u);              // LDS atomics: cheap, deterministic
    atomicAdd(&loadL[i2], 1u);
    // entropy: fixed-order butterfly within each wave, then wave partials
    #pragma unroll
    for (int off = 32; off; off >>= 1) ent += __shfl_xor(ent, off, 64);
    if ((tid & 63) == 0) entW[tid >> 6] = ent;
    __syncthreads();
    if (tid == 0) wsF[WS_ENTP + blockIdx.x] = entW[0] + entW[1];
    if (tid < E_) wsF[WS_LOADP + (size_t)blockIdx.x * E_ + tid] = (float)loadL[tid];
}

// finalize: one wave reduces 256 per-block partials (fixed order, determ.)
__global__ __launch_bounds__(64) void finalize_kernel(
    const float* __restrict__ wsF, float* __restrict__ out)
{
    int lane = threadIdx.x;                 // 64
    float ent = 0.f, ld[E_] = {0,0,0,0,0,0};
    #pragma unroll
    for (int q = 0; q < NPB / 64; ++q) {    // 4 blocks per lane
        int blk = lane * (NPB / 64) + q;
        ent += wsF[WS_ENTP + blk];
        #pragma unroll
        for (int e = 0; e < E_; ++e) ld[e] += wsF[WS_LOADP + (size_t)blk * E_ + e];
    }
    #pragma unroll
    for (int off = 32; off; off >>= 1) {
        ent += __shfl_xor(ent, off, 64);
        #pragma unroll
        for (int e = 0; e < E_; ++e) ld[e] += __shfl_xor(ld[e], off, 64);
    }
    if (lane == 0) {
        double m = 0.0;
        #pragma unroll
        for (int e = 0; e < E_; ++e) m += (double)ld[e];
        m /= (double)E_;
        double var = 0.0;
        #pragma unroll
        for (int e = 0; e < E_; ++e) { double d = (double)ld[e] - m; var += d * d; }
        var /= (double)(E_ - 1);
        // std(importance) == 0 exactly (top-2 always picks 2 of 6)
        double entm = (double)ent / (double)NTOK;
        out[(size_t)NTOK * E_ + (size_t)NTOK * 2] =
            (float)(0.1 * entm + 0.2 * sqrt(var));
    }
}

extern "C" void kernel_launch(void* const* d_in, const int* in_sizes, int n_in,
                              void* d_out, int out_size, void* d_ws, size_t ws_size,
                              hipStream_t stream)
{
    const float* x            = (const float*)d_in[0];
    const float* noise        = (const float*)d_in[1];
    const int*   expert_types = (const int*)  d_in[2];
    const float* type_emb     = (const float*)d_in[3];
    const float* nw1          = (const float*)d_in[4];
    const float* nb1          = (const float*)d_in[5];
    const float* nw2          = (const float*)d_in[6];
    const float* nb2          = (const float*)d_in[7];
    const float* rw1          = (const float*)d_in[8];
    const float* rb1          = (const float*)d_in[9];
    const float* rw2          = (const float*)d_in[10];
    const float* rb2          = (const float*)d_in[11];
    const float* temperature  = (const float*)d_in[12];
    float* out = (float*)d_out;
    float* wsF = (float*)d_ws;

    prep_kernel<<<NPK + 10, 256, 0, stream>>>(type_emb, rw1, rb1, rw2, rb2,
                                              temperature, nw1, wsF);
    router_mfma<<<(NTOK / TPB) * NS, 256, 0, stream>>>(x, nb1, nw2, nb2, wsF);
    router_post<<<NPB, 128, 0, stream>>>(noise, expert_types, wsF, out);
    finalize_kernel<<<1, 64, 0, stream>>>(wsF, out);
}